// Round 1
// baseline (1063.032 us; speedup 1.0000x reference)
//
#include <hip/hip_runtime.h>

// Volume dims (fixed by the reference): frames[T=3][Z=72][Y=512][X=1024], fp32.
#define TT 3
#define ZZ 72
#define YY 512
#define XX 1024
#define FRAME_STRIDE ((long)ZZ * YY * XX)   // 37,748,736 elements
#define ZSTRIDE      ((long)YY * XX)        // 524,288
#define YSTRIDE      ((long)XX)             // 1,024

// Bucketing: key = z0 * 8 + (y0 >> 6)  → 72 * 8 = 576 buckets.
// One bucket's gather footprint: 2 z-slabs × 2 y-blocks × 3 frames ≈ 3 MB (L2/L3-resident).
#define NB     576
#define SC_IPT 16      // items per thread in the scatter pass

// ---------------------------------------------------------------------------
// Shared trilerp math (identical to the harness-verified kernel).
// ---------------------------------------------------------------------------
__device__ __forceinline__ float trilerp_frame(
    const float* __restrict__ fr,
    long oz0y0, long oz0y1, long oz1y0, long oz1y1,
    int x0, int x1, float wz, float wy, float wx)
{
    float c000 = fr[oz0y0 + x0];
    float c001 = fr[oz0y0 + x1];
    float c010 = fr[oz0y1 + x0];
    float c011 = fr[oz0y1 + x1];
    float c100 = fr[oz1y0 + x0];
    float c101 = fr[oz1y0 + x1];
    float c110 = fr[oz1y1 + x0];
    float c111 = fr[oz1y1 + x1];
    float iwx = 1.0f - wx;
    float c00 = c000 * iwx + c001 * wx;
    float c01 = c010 * iwx + c011 * wx;
    float c10 = c100 * iwx + c101 * wx;
    float c11 = c110 * iwx + c111 * wx;
    float iwy = 1.0f - wy;
    float c0 = c00 * iwy + c01 * wy;
    float c1 = c10 * iwy + c11 * wy;
    return c0 * (1.0f - wz) + c1 * wz;
}

__device__ __forceinline__ float sample_one(float4 c, const float* __restrict__ frames)
{
    // temporal
    float t_abs = c.w * 3.0f;
    int t0 = (int)floorf(t_abs);
    t0 = min(max(t0, 0), TT - 1);
    float w = t_abs - (float)t0;
    int t1 = min(t0 + 1, TT - 1);

    // spatial
    float sz = c.x * (float)(ZZ - 1);
    float sy = c.y * (float)(YY - 1);
    float sx = c.z * (float)(XX - 1);
    int z0 = (int)sz;
    int y0 = (int)sy;
    int x0 = (int)sx;
    float wz = sz - (float)z0;   // weights from UNclamped idx (ref semantics)
    float wy = sy - (float)y0;
    float wx = sx - (float)x0;
    z0 = min(max(z0, 0), ZZ - 1);
    y0 = min(max(y0, 0), YY - 1);
    x0 = min(max(x0, 0), XX - 1);
    int z1 = min(z0 + 1, ZZ - 1);
    int y1 = min(y0 + 1, YY - 1);
    int x1 = min(x0 + 1, XX - 1);

    long oz0y0 = (long)z0 * ZSTRIDE + (long)y0 * YSTRIDE;
    long oz0y1 = (long)z0 * ZSTRIDE + (long)y1 * YSTRIDE;
    long oz1y0 = (long)z1 * ZSTRIDE + (long)y0 * YSTRIDE;
    long oz1y1 = (long)z1 * ZSTRIDE + (long)y1 * YSTRIDE;

    const float* f0 = frames + (long)t0 * FRAME_STRIDE;
    float v0 = trilerp_frame(f0, oz0y0, oz0y1, oz1y0, oz1y1, x0, x1, wz, wy, wx);

    float v1;
    if (t1 != t0) {
        const float* f1 = frames + (long)t1 * FRAME_STRIDE;
        v1 = trilerp_frame(f1, oz0y0, oz0y1, oz1y0, oz1y1, x0, x1, wz, wy, wx);
    } else {
        v1 = v0;   // t_abs in [2,3): both samples identical — skip 8 gathers
    }
    return v0 * (1.0f - w) + v1 * w;
}

__device__ __forceinline__ int bucket_key(float4 c)
{
    int z0 = (int)(c.x * (float)(ZZ - 1));
    int y0 = (int)(c.y * (float)(YY - 1));
    z0 = min(max(z0, 0), ZZ - 1);
    y0 = min(max(y0, 0), YY - 1);
    return z0 * 8 + (y0 >> 6);
}

// ---------------------------------------------------------------------------
// Pass 0: zero the histogram (kernel instead of hipMemsetAsync — capture-safe
// and idempotent across graph replays).
// ---------------------------------------------------------------------------
__global__ __launch_bounds__(1024) void zero_counts_kernel(int* __restrict__ counts)
{
    int t = threadIdx.x;
    if (t < NB) counts[t] = 0;
}

// ---------------------------------------------------------------------------
// Pass 1: histogram with per-block LDS aggregation.
// ---------------------------------------------------------------------------
__global__ __launch_bounds__(256) void hist_kernel(
    const float4* __restrict__ coords, int n, int* __restrict__ counts)
{
    __shared__ int lcnt[NB];
    for (int k = threadIdx.x; k < NB; k += 256) lcnt[k] = 0;
    __syncthreads();
    for (int i = blockIdx.x * 256 + threadIdx.x; i < n; i += gridDim.x * 256)
        atomicAdd(&lcnt[bucket_key(coords[i])], 1);
    __syncthreads();
    for (int k = threadIdx.x; k < NB; k += 256) {
        int v = lcnt[k];
        if (v) atomicAdd(&counts[k], v);
    }
}

// ---------------------------------------------------------------------------
// Pass 2: exclusive scan over NB counts (single block, Hillis–Steele in LDS).
// ---------------------------------------------------------------------------
__global__ __launch_bounds__(1024) void scan_kernel(
    const int* __restrict__ counts, int* __restrict__ offsets)
{
    __shared__ int buf[1024];
    int t = threadIdx.x;
    int my = (t < NB) ? counts[t] : 0;
    buf[t] = my;
    __syncthreads();
    for (int d = 1; d < 1024; d <<= 1) {
        int v = (t >= d) ? buf[t - d] : 0;
        __syncthreads();
        buf[t] += v;
        __syncthreads();
    }
    if (t < NB) offsets[t] = buf[t] - my;   // exclusive prefix
}

// ---------------------------------------------------------------------------
// Pass 3: scatter into bucket order. Per-block LDS ranks; one global
// atomicAdd per (block, non-empty bucket). Order within a bucket is
// arbitrary (doesn't affect correctness).
// ---------------------------------------------------------------------------
__global__ __launch_bounds__(256) void scatter_kernel(
    const float4* __restrict__ coords, int n,
    int* __restrict__ offsets,           // mutated; rebuilt by scan each replay
    float4* __restrict__ scoords, int* __restrict__ sidx)
{
    __shared__ int lcnt[NB];
    __shared__ int lbase[NB];
    for (int k = threadIdx.x; k < NB; k += 256) lcnt[k] = 0;
    __syncthreads();

    int base_i = blockIdx.x * (256 * SC_IPT) + threadIdx.x;
    float4 cs[SC_IPT];
    int keys[SC_IPT];
    int ranks[SC_IPT];
#pragma unroll
    for (int j = 0; j < SC_IPT; ++j) {
        int i = base_i + j * 256;
        if (i < n) {
            cs[j]    = coords[i];
            keys[j]  = bucket_key(cs[j]);
            ranks[j] = atomicAdd(&lcnt[keys[j]], 1);
        }
    }
    __syncthreads();
    for (int k = threadIdx.x; k < NB; k += 256) {
        int c = lcnt[k];
        lbase[k] = c ? atomicAdd(&offsets[k], c) : 0;
    }
    __syncthreads();
#pragma unroll
    for (int j = 0; j < SC_IPT; ++j) {
        int i = base_i + j * 256;
        if (i < n) {
            int pos = lbase[keys[j]] + ranks[j];
            scoords[pos] = cs[j];
            sidx[pos]    = i;
        }
    }
}

// ---------------------------------------------------------------------------
// Pass 4: main sampling over the bucket-ordered coords. Consecutive blocks
// share a ~3 MB gather window → L2/L3 hits instead of random HBM.
// Bijective XCD-chunked swizzle (m204 form) so each XCD's private L2 sees a
// contiguous sliding window of the sorted array.
// ---------------------------------------------------------------------------
__global__ __launch_bounds__(256) void sorted_kernel(
    const float4* __restrict__ scoords, const int* __restrict__ sidx,
    const float*  __restrict__ frames,  float* __restrict__ out, int n)
{
    int nwg  = gridDim.x;
    int orig = blockIdx.x;
    int xcd  = orig & 7;
    int q = nwg >> 3, r = nwg & 7;
    int wg = (xcd < r ? xcd * (q + 1) : r * (q + 1) + (xcd - r) * q) + (orig >> 3);

    int i = wg * 256 + threadIdx.x;
    if (i >= n) return;

    float4 c = scoords[i];
    float v = sample_one(c, frames);
    out[sidx[i]] = v;
}

// ---------------------------------------------------------------------------
// Fallback: the previous harness-verified direct kernel (used if the
// workspace is too small for the sort buffers).
// ---------------------------------------------------------------------------
__global__ __launch_bounds__(256) void direct_kernel(
    const float4* __restrict__ coords, const float* __restrict__ frames,
    float* __restrict__ out, int n)
{
    int i = blockIdx.x * blockDim.x + threadIdx.x;
    if (i >= n) return;
    out[i] = sample_one(coords[i], frames);
}

extern "C" void kernel_launch(void* const* d_in, const int* in_sizes, int n_in,
                              void* d_out, int out_size, void* d_ws, size_t ws_size,
                              hipStream_t stream) {
    const float4* coords = (const float4*)d_in[0];   // N*4 floats
    const float*  frames = (const float*)d_in[1];    // T*Z*Y*X floats
    float* out = (float*)d_out;                      // N floats
    int n = in_sizes[0] / 4;

    // Workspace layout: [ sorted coords: n*16 | sorted idx: n*4 | counts: NB*4 | offsets: NB*4 ]
    size_t required = (size_t)n * 20 + (size_t)NB * 8 + 256;

    if (d_ws == nullptr || ws_size < required) {
        // Fallback: direct path (previous verified kernel, ~1043 µs).
        int block = 256;
        int grid = (n + block - 1) / block;
        direct_kernel<<<grid, block, 0, stream>>>(coords, frames, out, n);
        return;
    }

    float4* scoords = (float4*)d_ws;
    int*    sidx    = (int*)((char*)d_ws + (size_t)n * 16);
    int*    counts  = (int*)((char*)d_ws + (size_t)n * 20);
    int*    offsets = counts + NB;

    // Pass 0: zero histogram (graph-replay idempotent).
    zero_counts_kernel<<<1, 1024, 0, stream>>>(counts);

    // Pass 1: histogram.
    int hist_grid = min(2048, (n + 255) / 256);
    hist_kernel<<<hist_grid, 256, 0, stream>>>(coords, n, counts);

    // Pass 2: exclusive scan (offsets fully rewritten each replay).
    scan_kernel<<<1, 1024, 0, stream>>>(counts, offsets);

    // Pass 3: scatter into bucket order.
    int sc_grid = (n + 256 * SC_IPT - 1) / (256 * SC_IPT);
    scatter_kernel<<<sc_grid, 256, 0, stream>>>(coords, n, offsets, scoords, sidx);

    // Pass 4: locality-ordered sampling.
    int grid = (n + 255) / 256;
    sorted_kernel<<<grid, 256, 0, stream>>>(scoords, sidx, frames, out, n);
}

// Round 5
// 951.355 us; speedup vs baseline: 1.1174x; 1.1174x over previous
//
#include <hip/hip_runtime.h>

// Volume dims (fixed by the reference): frames[T=3][Z=72][Y=512][X=1024], fp32.
#define TT 3
#define ZZ 72
#define YY 512
#define XX 1024
#define FRAME_STRIDE ((long)ZZ * YY * XX)   // 37,748,736 elements
#define ZSTRIDE      ((long)YY * XX)        // 524,288
#define YSTRIDE      ((long)XX)             // 1,024

// Bucketing: key = z0 * 8 + (y0 >> 6)  → 72 * 8 = 576 buckets.
// Window per bucket: 2 z-slabs × 65 y-rows × 1024 x × 3 frames ≈ 1.6 MB (L2-resident).
#define NB    576
// Fixed slots per bucket. Uniform mean = N/NB = 7282, sd ≈ 85 → 8192 = +10.7σ.
// Overflow items are sampled INLINE in the bin pass (correct for any distribution).
#define CAP   8192
#define MBPB  (CAP / 256)   // main-pass blocks per bucket = 32
// One global counter per 64B line (R1: 1.8M atomics over 36 shared lines ≈ 620us).
#define CPAD  16
#define IPT   16            // items per thread in the bin pass
#define WARM  1             // sequential pre-touch of each bucket's fresh slab

// ---------------------------------------------------------------------------
// Shared trilerp math (identical to the harness-verified kernel).
// ---------------------------------------------------------------------------
__device__ __forceinline__ float trilerp_frame(
    const float* __restrict__ fr,
    long oz0y0, long oz0y1, long oz1y0, long oz1y1,
    int x0, int x1, float wz, float wy, float wx)
{
    float c000 = fr[oz0y0 + x0];
    float c001 = fr[oz0y0 + x1];
    float c010 = fr[oz0y1 + x0];
    float c011 = fr[oz0y1 + x1];
    float c100 = fr[oz1y0 + x0];
    float c101 = fr[oz1y0 + x1];
    float c110 = fr[oz1y1 + x0];
    float c111 = fr[oz1y1 + x1];
    float iwx = 1.0f - wx;
    float c00 = c000 * iwx + c001 * wx;
    float c01 = c010 * iwx + c011 * wx;
    float c10 = c100 * iwx + c101 * wx;
    float c11 = c110 * iwx + c111 * wx;
    float iwy = 1.0f - wy;
    float c0 = c00 * iwy + c01 * wy;
    float c1 = c10 * iwy + c11 * wy;
    return c0 * (1.0f - wz) + c1 * wz;
}

__device__ __forceinline__ float sample_one(float4 c, const float* __restrict__ frames)
{
    // temporal
    float t_abs = c.w * 3.0f;
    int t0 = (int)floorf(t_abs);
    t0 = min(max(t0, 0), TT - 1);
    float w = t_abs - (float)t0;
    int t1 = min(t0 + 1, TT - 1);

    // spatial
    float sz = c.x * (float)(ZZ - 1);
    float sy = c.y * (float)(YY - 1);
    float sx = c.z * (float)(XX - 1);
    int z0 = (int)sz;
    int y0 = (int)sy;
    int x0 = (int)sx;
    float wz = sz - (float)z0;   // weights from UNclamped idx (ref semantics)
    float wy = sy - (float)y0;
    float wx = sx - (float)x0;
    z0 = min(max(z0, 0), ZZ - 1);
    y0 = min(max(y0, 0), YY - 1);
    x0 = min(max(x0, 0), XX - 1);
    int z1 = min(z0 + 1, ZZ - 1);
    int y1 = min(y0 + 1, YY - 1);
    int x1 = min(x0 + 1, XX - 1);

    long oz0y0 = (long)z0 * ZSTRIDE + (long)y0 * YSTRIDE;
    long oz0y1 = (long)z0 * ZSTRIDE + (long)y1 * YSTRIDE;
    long oz1y0 = (long)z1 * ZSTRIDE + (long)y0 * YSTRIDE;
    long oz1y1 = (long)z1 * ZSTRIDE + (long)y1 * YSTRIDE;

    const float* f0 = frames + (long)t0 * FRAME_STRIDE;
    float v0 = trilerp_frame(f0, oz0y0, oz0y1, oz1y0, oz1y1, x0, x1, wz, wy, wx);

    float v1;
    if (t1 != t0) {
        const float* f1 = frames + (long)t1 * FRAME_STRIDE;
        v1 = trilerp_frame(f1, oz0y0, oz0y1, oz1y0, oz1y1, x0, x1, wz, wy, wx);
    } else {
        v1 = v0;   // t_abs in [2,3): both samples identical — skip 8 gathers
    }
    return v0 * (1.0f - w) + v1 * w;
}

__device__ __forceinline__ int bucket_key(float4 c)
{
    int z0 = (int)(c.x * (float)(ZZ - 1));
    int y0 = (int)(c.y * (float)(YY - 1));
    z0 = min(max(z0, 0), ZZ - 1);
    y0 = min(max(y0, 0), YY - 1);
    return z0 * 8 + (y0 >> 6);
}

// ---------------------------------------------------------------------------
// Pass 0: zero the padded counters (capture-safe, replay-idempotent).
// ---------------------------------------------------------------------------
__global__ __launch_bounds__(1024) void zero_counts_kernel(int* __restrict__ counts)
{
    int t = threadIdx.x;
    if (t < NB) counts[t * CPAD] = 0;
}

// ===========================================================================
// C-tier: record slots (float4 coords) + rank array + tmp values + permute.
// ===========================================================================

// Pass 1: fused binning. Stores the full coord record per slot (main pass
// reads records SEQUENTIALLY — no coords re-gather) and rank[i] = global slot
// (written coalesced). Overflow (slot >= CAP): sample inline, rank[i] = -1.
__global__ __launch_bounds__(256) void bin_rec_kernel(
    const float4* __restrict__ coords, int n,
    int*    __restrict__ counts,     // NB padded counters (zeroed by pass 0)
    float4* __restrict__ scoords,    // NB*CAP coord records
    int*    __restrict__ rank,       // n: global slot or -1
    const float* __restrict__ frames, float* __restrict__ out)
{
    __shared__ int lcnt[NB];
    __shared__ int lbase[NB];
    for (int k = threadIdx.x; k < NB; k += 256) lcnt[k] = 0;
    __syncthreads();

    int base_i = blockIdx.x * (256 * IPT) + threadIdx.x;
    float4 cs[IPT];
    int keys[IPT];
    int ranks[IPT];
#pragma unroll
    for (int j = 0; j < IPT; ++j) {
        int i = base_i + j * 256;
        if (i < n) {
            cs[j]    = coords[i];
            keys[j]  = bucket_key(cs[j]);
            ranks[j] = atomicAdd(&lcnt[keys[j]], 1);
        }
    }
    __syncthreads();
    for (int k = threadIdx.x; k < NB; k += 256) {
        int c = lcnt[k];
        lbase[k] = c ? atomicAdd(&counts[k * CPAD], c) : 0;
    }
    __syncthreads();
#pragma unroll
    for (int j = 0; j < IPT; ++j) {
        int i = base_i + j * 256;
        if (i < n) {
            int s = lbase[keys[j]] + ranks[j];
            if (s < CAP) {
                int g = keys[j] * CAP + s;
                scoords[g] = cs[j];
                rank[i] = g;
            } else {
                rank[i] = -1;
                out[i] = sample_one(cs[j], frames);   // cold path
            }
        }
    }
}

// Pass 2: sampling in bucket order. Each bucket's 32 blocks first SEQUENTIALLY
// pre-touch a disjoint 1/32 slice of the bucket's fresh slab (zg+1, 3 frames,
// 64 rows = 768 KB) — converts the HBM first-touch stream from random to
// sequential (R1: random first-touch ran at 1.53 TB/s). Slab zg was warmed by
// the previous z-group on the same XCD (chunk = 9 z-levels). Then sample
// records sequentially and write values to tmp sequentially.
__global__ __launch_bounds__(256) void main_rec_kernel(
    const float4* __restrict__ scoords, const int* __restrict__ counts,
    const float*  __restrict__ frames,  float* __restrict__ tmp)
{
    int nwg  = gridDim.x;                 // NB*MBPB = 18432 (divisible by 8)
    int orig = blockIdx.x;
    int xcd  = orig & 7;
    int q = nwg >> 3, r = nwg & 7;
    int wg = (xcd < r ? xcd * (q + 1) : r * (q + 1) + (xcd - r) * q) + (orig >> 3);

    int bucket = wg / MBPB;
    int br     = wg % MBPB;               // this block's rank within the bucket

#if WARM
    {
        int zg = bucket >> 3;
        int yg = bucket & 7;
        int zs = (zg + 1 < ZZ) ? (zg + 1) : (ZZ - 1);
        float acc = 0.0f;
        int npass = (zg == 0) ? 2 : 1;    // z=0 buckets also warm slab 0
        for (int pass = 0; pass < npass; ++pass) {
            int zslab = pass ? 0 : zs;
            // fresh region: 3 frames x 64 rows x 256 float4 = 49152 float4
            // slice br: 1536 float4; per thread: 6
#pragma unroll
            for (int k = 0; k < 6; ++k) {
                int idx4 = br * 1536 + k * 256 + (int)threadIdx.x;
                int f    = idx4 >> 14;          // / (64*256)
                int rem  = idx4 & 16383;
                int ry   = rem >> 8;
                int c4   = rem & 255;
                const float* p = frames + (long)f * FRAME_STRIDE
                               + (long)zslab * ZSTRIDE
                               + (long)(yg * 64 + ry) * YSTRIDE
                               + (long)(c4 * 4);
                float4 v = *(const float4*)p;
                acc += v.x + v.y + v.z + v.w;
            }
        }
        asm volatile("" :: "v"(acc));       // keep warm loads live (rule #17)
    }
#endif

    int cnt = min(counts[bucket * CPAD], CAP);
    int slot = br * 256 + threadIdx.x;
    if (slot >= cnt) return;

    int g = bucket * CAP + slot;
    tmp[g] = sample_one(scoords[g], frames);
}

// Pass 3: permute — out[i] = tmp[rank[i]]. rank read via int4 (coalesced),
// tmp gather is over a 19 MB resident array, out written ~sequentially.
// rank < 0 (overflow): out[i] was already written by the bin pass — skip.
__global__ __launch_bounds__(256) void permute_kernel(
    const int* __restrict__ rank, const float* __restrict__ tmp,
    float* __restrict__ out, int n)
{
    int i4 = blockIdx.x * 256 + threadIdx.x;
    int i  = i4 * 4;
    if (i + 3 < n) {
        int4 rr = *(const int4*)(rank + i);
        if (rr.x >= 0) out[i + 0] = tmp[rr.x];
        if (rr.y >= 0) out[i + 1] = tmp[rr.y];
        if (rr.z >= 0) out[i + 2] = tmp[rr.z];
        if (rr.w >= 0) out[i + 3] = tmp[rr.w];
    } else {
        for (int e = i; e < n; ++e) {
            int r = rank[e];
            if (r >= 0) out[e] = tmp[r];
        }
    }
}

// ===========================================================================
// A-tier fallback: index-only slots (19 MB ws), gather coords, scatter out.
// ===========================================================================
__global__ __launch_bounds__(256) void bin_idx_kernel(
    const float4* __restrict__ coords, int n,
    int* __restrict__ counts, int* __restrict__ sidx,
    const float* __restrict__ frames, float* __restrict__ out)
{
    __shared__ int lcnt[NB];
    __shared__ int lbase[NB];
    for (int k = threadIdx.x; k < NB; k += 256) lcnt[k] = 0;
    __syncthreads();

    int base_i = blockIdx.x * (256 * IPT) + threadIdx.x;
    float4 cs[IPT];
    int keys[IPT];
    int ranks[IPT];
#pragma unroll
    for (int j = 0; j < IPT; ++j) {
        int i = base_i + j * 256;
        if (i < n) {
            cs[j]    = coords[i];
            keys[j]  = bucket_key(cs[j]);
            ranks[j] = atomicAdd(&lcnt[keys[j]], 1);
        }
    }
    __syncthreads();
    for (int k = threadIdx.x; k < NB; k += 256) {
        int c = lcnt[k];
        lbase[k] = c ? atomicAdd(&counts[k * CPAD], c) : 0;
    }
    __syncthreads();
#pragma unroll
    for (int j = 0; j < IPT; ++j) {
        int i = base_i + j * 256;
        if (i < n) {
            int s = lbase[keys[j]] + ranks[j];
            if (s < CAP) sidx[keys[j] * CAP + s] = i;
            else         out[i] = sample_one(cs[j], frames);
        }
    }
}

__global__ __launch_bounds__(256) void main_idx_kernel(
    const int*    __restrict__ sidx,   const int* __restrict__ counts,
    const float4* __restrict__ coords, const float* __restrict__ frames,
    float* __restrict__ out)
{
    int nwg  = gridDim.x;
    int orig = blockIdx.x;
    int xcd  = orig & 7;
    int q = nwg >> 3, r = nwg & 7;
    int wg = (xcd < r ? xcd * (q + 1) : r * (q + 1) + (xcd - r) * q) + (orig >> 3);

    int bucket   = wg / MBPB;
    int slotbase = (wg % MBPB) * 256;

    int cnt = min(counts[bucket * CPAD], CAP);
    int slot = slotbase + threadIdx.x;
    if (slot >= cnt) return;

    int j = sidx[bucket * CAP + slot];
    float4 c = coords[j];
    out[j] = sample_one(c, frames);
}

// ---------------------------------------------------------------------------
// Last-resort fallback: direct kernel.
// ---------------------------------------------------------------------------
__global__ __launch_bounds__(256) void direct_kernel(
    const float4* __restrict__ coords, const float* __restrict__ frames,
    float* __restrict__ out, int n)
{
    int i = blockIdx.x * blockDim.x + threadIdx.x;
    if (i >= n) return;
    out[i] = sample_one(coords[i], frames);
}

extern "C" void kernel_launch(void* const* d_in, const int* in_sizes, int n_in,
                              void* d_out, int out_size, void* d_ws, size_t ws_size,
                              hipStream_t stream) {
    const float4* coords = (const float4*)d_in[0];   // N*4 floats
    const float*  frames = (const float*)d_in[1];    // T*Z*Y*X floats
    float* out = (float*)d_out;                      // N floats
    int n = in_sizes[0] / 4;

    size_t scoords_b = (size_t)NB * CAP * 16;        // 75.5 MB
    size_t tmp_b     = (size_t)NB * CAP * 4;         // 18.9 MB
    size_t rank_b    = (size_t)n * 4;                // 16.8 MB
    size_t counts_b  = (size_t)NB * CPAD * 4;        // 37 KB
    size_t reqC = scoords_b + tmp_b + rank_b + counts_b + 256;   // ~111.2 MB
    size_t reqA = (size_t)NB * CAP * 4 + counts_b + 256;         // ~18.9 MB

    if (d_ws != nullptr && ws_size >= reqC) {
        float4* scoords = (float4*)d_ws;
        float*  tmp     = (float*)((char*)d_ws + scoords_b);
        int*    rank    = (int*)((char*)d_ws + scoords_b + tmp_b);
        int*    counts  = (int*)((char*)d_ws + scoords_b + tmp_b + rank_b);

        zero_counts_kernel<<<1, 1024, 0, stream>>>(counts);
        int bin_grid = (n + 256 * IPT - 1) / (256 * IPT);
        bin_rec_kernel<<<bin_grid, 256, 0, stream>>>(coords, n, counts, scoords,
                                                     rank, frames, out);
        main_rec_kernel<<<NB * MBPB, 256, 0, stream>>>(scoords, counts, frames, tmp);
        int perm_grid = (n + 1023) / 1024;
        permute_kernel<<<perm_grid, 256, 0, stream>>>(rank, tmp, out, n);
    } else if (d_ws != nullptr && ws_size >= reqA) {
        int* sidx   = (int*)d_ws;
        int* counts = (int*)((char*)d_ws + (size_t)NB * CAP * 4);

        zero_counts_kernel<<<1, 1024, 0, stream>>>(counts);
        int bin_grid = (n + 256 * IPT - 1) / (256 * IPT);
        bin_idx_kernel<<<bin_grid, 256, 0, stream>>>(coords, n, counts, sidx,
                                                     frames, out);
        main_idx_kernel<<<NB * MBPB, 256, 0, stream>>>(sidx, counts, coords,
                                                       frames, out);
    } else {
        int grid = (n + 255) / 256;
        direct_kernel<<<grid, 256, 0, stream>>>(coords, frames, out, n);
    }
}